// Round 2
// baseline (1047.270 us; speedup 1.0000x reference)
//
#include <hip/hip_runtime.h>
#include <hip/hip_bf16.h>
#include <stdint.h>

#define SQ   1024
#define NB   8
#define HD   1024
#define NHD  16
#define DKK  64
// bh = NHD*NB = 128

typedef __bf16 bf16x8_t __attribute__((ext_vector_type(8)));
typedef float  f32x4_t  __attribute__((ext_vector_type(4)));
typedef __hip_bfloat16 bf16;

__device__ __forceinline__ void gld_lds16(const void* g, void* l) {
    __builtin_amdgcn_global_load_lds(
        (__attribute__((address_space(1))) void*)const_cast<void*>(g),
        (__attribute__((address_space(3))) void*)l,
        16, 0, 0);
}

__device__ __forceinline__ bf16x8_t cvt8(float4 a, float4 b) {
    bf16x8_t r;
    r[0] = (__bf16)a.x; r[1] = (__bf16)a.y; r[2] = (__bf16)a.z; r[3] = (__bf16)a.w;
    r[4] = (__bf16)b.x; r[5] = (__bf16)b.y; r[6] = (__bf16)b.z; r[7] = (__bf16)b.w;
    return r;
}

// ---------------------------------------------------------------------------
// GEMM: C[m,o] = sum_k A[m,k] * W[o,k]   (A: 8192x1024, W: 1024x1024)
// W always f32 (cvt-staged). mode 0: A f32, Out = bf16 head-major scatter
//   Out[((o>>6)*8 + (m&7))*1024 + (m>>3)]*64 + (o&63)
// mode 1: A bf16 (global_load_lds), Out = f32 row-major Out[m*1024 + o]
// ---------------------------------------------------------------------------
__global__ __launch_bounds__(256, 2)
void gemm_kernel(const void* __restrict__ A0, const void* __restrict__ A1,
                 const void* __restrict__ A2,
                 const float* __restrict__ W0, const float* __restrict__ W1,
                 const float* __restrict__ W2,
                 void* __restrict__ O0, void* __restrict__ O1,
                 void* __restrict__ O2, int mode)
{
    const int z = blockIdx.z;
    const void*  A  = (z == 0) ? A0 : (z == 1) ? A1 : A2;
    const float* Wf = (z == 0) ? W0 : (z == 1) ? W1 : W2;
    void*        Ov = (z == 0) ? O0 : (z == 1) ? O1 : O2;

    __shared__ alignas(16) bf16 lA[128 * 32];
    __shared__ alignas(16) bf16 lB[128 * 32];

    const int tid  = threadIdx.x;
    const int lane = tid & 63;
    const int w    = tid >> 6;
    const int wr   = w >> 1;
    const int wc   = w & 1;
    const int g    = lane >> 4;
    const int ln   = lane & 15;
    const int bm   = blockIdx.y;
    const int bn   = blockIdx.x;

    f32x4_t acc[4][4];
#pragma unroll
    for (int i = 0; i < 4; ++i)
#pragma unroll
        for (int j = 0; j < 4; ++j)
            acc[i][j] = (f32x4_t){0.f, 0.f, 0.f, 0.f};

    const size_t arow0 = (size_t)bm * 128;
    const size_t brow0 = (size_t)bn * 128;
    const float* Af  = (const float*)A;
    const bf16*  Ab  = (const bf16*)A;

    for (int k0 = 0; k0 < HD; k0 += 32) {
#pragma unroll
        for (int q = 0; q < 2; ++q) {
            const int cid = (q * 4 + w) * 64 + lane;
            const int r   = cid >> 2;
            const int gch = (cid & 3) ^ ((r ^ (r >> 2)) & 3);   // bank swizzle
            if (mode == 0) {
                const float4* src = (const float4*)(Af + (arow0 + r) * HD + k0 + gch * 8);
                *(bf16x8_t*)&lA[cid * 8] = cvt8(src[0], src[1]);
            } else {
                gld_lds16((const char*)Ab + ((arow0 + r) * HD + k0) * 2 + gch * 16,
                          (char*)lA + cid * 16);
            }
            const float4* wsrc = (const float4*)(Wf + (brow0 + r) * HD + k0 + gch * 8);
            *(bf16x8_t*)&lB[cid * 8] = cvt8(wsrc[0], wsrc[1]);
        }
        __syncthreads();
        bf16x8_t av[4], bv[4];
#pragma unroll
        for (int mi = 0; mi < 4; ++mi) {
            const int row = wr * 64 + mi * 16 + ln;
            av[mi] = *(const bf16x8_t*)&lA[row * 32 + ((g ^ ((row ^ (row >> 2)) & 3)) << 3)];
        }
#pragma unroll
        for (int ni = 0; ni < 4; ++ni) {
            const int row = wc * 64 + ni * 16 + ln;
            bv[ni] = *(const bf16x8_t*)&lB[row * 32 + ((g ^ ((row ^ (row >> 2)) & 3)) << 3)];
        }
#pragma unroll
        for (int mi = 0; mi < 4; ++mi)
#pragma unroll
            for (int ni = 0; ni < 4; ++ni)
                acc[mi][ni] = __builtin_amdgcn_mfma_f32_16x16x32_bf16(
                    av[mi], bv[ni], acc[mi][ni], 0, 0, 0);
        __syncthreads();
    }

    bf16*  Ob = (bf16*)Ov;
    float* Of = (float*)Ov;
#pragma unroll
    for (int mi = 0; mi < 4; ++mi) {
#pragma unroll
        for (int ni = 0; ni < 4; ++ni) {
            const int o = bn * 128 + wc * 64 + ni * 16 + ln;
#pragma unroll
            for (int r = 0; r < 4; ++r) {
                const int m = bm * 128 + wr * 64 + mi * 16 + g * 4 + r;
                const float v = acc[mi][ni][r];
                if (mode == 0) {
                    const int h = o >> 6, d = o & 63;
                    const int s = m >> 3, b = m & 7;
                    Ob[(((size_t)(h * 8 + b) * SQ + s) << 6) + d] = __float2bfloat16(v);
                } else {
                    Of[(size_t)m * HD + o] = v;
                }
            }
        }
    }
}

// ---------------------------------------------------------------------------
// K2: per (bh, i-block of 64): scores = K.Q^T/8 with mask (j>i -> -inf),
// softmax over j (reference axis=2), write f32 dist[bh][i][j].
// Pass A: row sums of exp (no max subtraction: |s| <~ 3). Pass B: recompute,
// normalize, write; zero-fill fully-masked tiles.
// ---------------------------------------------------------------------------
__global__ __launch_bounds__(256, 2)
void scores_softmax_kernel(const bf16* __restrict__ Kh, const bf16* __restrict__ Qh,
                           float* __restrict__ Dist)
{
    __shared__ alignas(16) bf16 Kl[64 * 64];
    __shared__ alignas(16) bf16 Ql[64 * 64];
    const int tid = threadIdx.x, lane = tid & 63, w = tid >> 6;
    const int g = lane >> 4, ln = lane & 15;
    const int ib = blockIdx.x, bh = blockIdx.y;
    const char* Kp = (const char*)(Kh + ((size_t)bh * SQ + ib * 64) * DKK);
    const char* Qp = (const char*)(Qh + (size_t)bh * SQ * DKK);
    float* Dp = Dist + (size_t)bh * SQ * SQ;

#pragma unroll
    for (int q = 0; q < 2; ++q) {
        const int cid = (q * 4 + w) * 64 + lane;
        const int r   = cid >> 3;
        const int cc  = (cid & 7) ^ ((r ^ (r >> 3)) & 7);
        gld_lds16(Kp + r * 128 + cc * 16, (char*)Kl + cid * 16);
    }
    __syncthreads();
    const int arow = w * 16 + ln;
    const int asw  = (arow ^ (arow >> 3)) & 7;
    const bf16x8_t ak0 = *(const bf16x8_t*)&Kl[arow * 64 + ((g ^ asw) << 3)];
    const bf16x8_t ak1 = *(const bf16x8_t*)&Kl[arow * 64 + (((4 + g) ^ asw) << 3)];

    const int irow = ib * 64 + w * 16 + g * 4;   // + r gives global key row i

    auto stage_q = [&](int jt) {
#pragma unroll
        for (int q = 0; q < 2; ++q) {
            const int cid = (q * 4 + w) * 64 + lane;
            const int r   = cid >> 3;
            const int cc  = (cid & 7) ^ ((r ^ (r >> 3)) & 7);
            gld_lds16(Qp + (size_t)jt * 8192 + r * 128 + cc * 16, (char*)Ql + cid * 16);
        }
    };
    auto compute_tile = [&](f32x4_t* accp) {
#pragma unroll
        for (int nf = 0; nf < 4; ++nf) {
            const int brow = nf * 16 + ln;
            const int bsw  = (brow ^ (brow >> 3)) & 7;
            bf16x8_t b0 = *(const bf16x8_t*)&Ql[brow * 64 + ((g ^ bsw) << 3)];
            bf16x8_t b1 = *(const bf16x8_t*)&Ql[brow * 64 + (((4 + g) ^ bsw) << 3)];
            f32x4_t a = (f32x4_t){0.f, 0.f, 0.f, 0.f};
            a = __builtin_amdgcn_mfma_f32_16x16x32_bf16(ak0, b0, a, 0, 0, 0);
            a = __builtin_amdgcn_mfma_f32_16x16x32_bf16(ak1, b1, a, 0, 0, 0);
            accp[nf] = a;
        }
    };

    float lsum[4] = {0.f, 0.f, 0.f, 0.f};
    for (int jt = 0; jt <= ib; ++jt) {
        __syncthreads();
        stage_q(jt);
        __syncthreads();
        f32x4_t acc[4];
        compute_tile(acc);
        float part[4] = {0.f, 0.f, 0.f, 0.f};
#pragma unroll
        for (int nf = 0; nf < 4; ++nf) {
            const int j = jt * 64 + nf * 16 + ln;
#pragma unroll
            for (int r = 0; r < 4; ++r) {
                const float s = acc[nf][r] * 0.125f;
                part[r] += (j <= irow + r) ? __expf(s) : 0.f;
            }
        }
#pragma unroll
        for (int r = 0; r < 4; ++r) {
            float p = part[r];
            p += __shfl_xor(p, 1);
            p += __shfl_xor(p, 2);
            p += __shfl_xor(p, 4);
            p += __shfl_xor(p, 8);
            lsum[r] += p;
        }
    }
    float inv[4];
#pragma unroll
    for (int r = 0; r < 4; ++r) inv[r] = 1.f / lsum[r];

    for (int jt = 0; jt < 16; ++jt) {
        if (jt <= ib) {
            __syncthreads();
            stage_q(jt);
            __syncthreads();
            f32x4_t acc[4];
            compute_tile(acc);
#pragma unroll
            for (int nf = 0; nf < 4; ++nf) {
                const int j = jt * 64 + nf * 16 + ln;
#pragma unroll
                for (int r = 0; r < 4; ++r) {
                    const float e = (j <= irow + r)
                        ? __expf(acc[nf][r] * 0.125f) * inv[r] : 0.f;
                    Dp[(size_t)(irow + r) * SQ + j] = e;
                }
            }
        } else {
            const uint4 zz = make_uint4(0u, 0u, 0u, 0u);
#pragma unroll
            for (int q = 0; q < 4; ++q) {
                const int cid = q * 256 + tid;
                const int row = cid >> 4;
                float* p = Dp + (size_t)(ib * 64 + row) * SQ + jt * 64 + (cid & 15) * 4;
                *(uint4*)p = zz;
            }
        }
    }
}

// ---------------------------------------------------------------------------
// K3: att[j,d] = sum_{i>=j} dist[i,j] * V[i,d] per bh.
// Tiles of 64 i; dist (f32, cvt->bf16) & V (bf16) transposed through LDS
// (pad 72 + xor swizzle). Writes att4[(j*8+b)*1024 + h*64 + d].
// ---------------------------------------------------------------------------
__global__ __launch_bounds__(256, 2)
void att_v_kernel(const float* __restrict__ Dist, const bf16* __restrict__ Vh,
                  bf16* __restrict__ att4)
{
    __shared__ alignas(16) bf16 dT[64 * 72];
    __shared__ alignas(16) bf16 vT[64 * 72];
    const int tid = threadIdx.x, lane = tid & 63, w = tid >> 6;
    const int g = lane >> 4, ln = lane & 15;
    const int jb = blockIdx.x, bh = blockIdx.y;
    const float* Dp = Dist + (size_t)bh * SQ * SQ;
    const bf16*  Vp = Vh + (size_t)bh * SQ * DKK;

    f32x4_t acc[4];
#pragma unroll
    for (int nf = 0; nf < 4; ++nf) acc[nf] = (f32x4_t){0.f, 0.f, 0.f, 0.f};

    unsigned short* dTs = (unsigned short*)dT;
    unsigned short* vTs = (unsigned short*)vT;

    for (int it = jb; it < 16; ++it) {
        __syncthreads();
        // stage dist: f32 -> bf16, transposed dT[j][i_swz]
#pragma unroll
        for (int q = 0; q < 4; ++q) {
            const int cid = q * 256 + tid;
            const int i   = cid >> 4;
            const int jc  = (cid & 15) * 4;
            float4 dv = *(const float4*)(Dp + ((size_t)(it * 64 + i) * SQ + jb * 64 + jc));
            const float de[4] = {dv.x, dv.y, dv.z, dv.w};
#pragma unroll
            for (int e = 0; e < 4; ++e) {
                const int j   = jc + e;
                const int isw = i ^ (((j >> 3) & 7) << 3);
                bf16 bv = __float2bfloat16(de[e]);
                dTs[j * 72 + isw] = *(unsigned short*)&bv;
            }
        }
        // stage V: bf16, transposed vT[d][i_swz]
#pragma unroll
        for (int q = 0; q < 2; ++q) {
            const int cid = q * 256 + tid;
            const int i   = cid >> 3;
            const int dc  = (cid & 7) * 8;
            uint4 vvec = *(const uint4*)(Vp + ((size_t)(it * 64 + i) * DKK + dc));
            const unsigned short* vs = (const unsigned short*)&vvec;
#pragma unroll
            for (int e = 0; e < 8; ++e) {
                const int d   = dc + e;
                const int isw = i ^ (((d >> 3) & 7) << 3);
                vTs[d * 72 + isw] = vs[e];
            }
        }
        __syncthreads();
#pragma unroll
        for (int kk = 0; kk < 2; ++kk) {
            const int arow  = w * 16 + ln;
            const int abase = (kk * 32 + g * 8) ^ (((arow >> 3) & 7) << 3);
            bf16x8_t a = *(const bf16x8_t*)&dT[arow * 72 + abase];
#pragma unroll
            for (int nf = 0; nf < 4; ++nf) {
                const int brow  = nf * 16 + ln;
                const int bbase = (kk * 32 + g * 8) ^ (((brow >> 3) & 7) << 3);
                bf16x8_t b = *(const bf16x8_t*)&vT[brow * 72 + bbase];
                acc[nf] = __builtin_amdgcn_mfma_f32_16x16x32_bf16(a, b, acc[nf], 0, 0, 0);
            }
        }
    }
    const int h = bh >> 3, b = bh & 7;
#pragma unroll
    for (int nf = 0; nf < 4; ++nf) {
#pragma unroll
        for (int r = 0; r < 4; ++r) {
            const int j = jb * 64 + w * 16 + g * 4 + r;
            att4[(size_t)(j * 8 + b) * HD + h * 64 + nf * 16 + ln] =
                __float2bfloat16(acc[nf][r]);
        }
    }
}

// ---------------------------------------------------------------------------
extern "C" void kernel_launch(void* const* d_in, const int* in_sizes, int n_in,
                              void* d_out, int out_size, void* d_ws, size_t ws_size,
                              hipStream_t stream)
{
    const float* value = (const float*)d_in[0];
    const float* key_  = (const float*)d_in[1];
    const float* query = (const float*)d_in[2];
    const float* Wq    = (const float*)d_in[3];
    const float* Wk    = (const float*)d_in[4];
    const float* Wv    = (const float*)d_in[5];
    const float* Wo    = (const float*)d_in[6];

    float* out  = (float*)d_out;                       // (S,B,H) f32
    float* dist = out + (size_t)SQ * NB * HD;          // (128,1024,1024) f32

    char* ws   = (char*)d_ws;
    bf16* Qh   = (bf16*)(ws);                          // 16 MB each
    bf16* Kh   = (bf16*)(ws + (size_t)16 * 1024 * 1024);
    bf16* Vh   = (bf16*)(ws + (size_t)32 * 1024 * 1024);
    bf16* att4 = (bf16*)(ws + (size_t)48 * 1024 * 1024);

    dim3 blk(256);
    // K1: projections (f32 in) -> head-major bf16 Qh/Kh/Vh
    gemm_kernel<<<dim3(8, 64, 3), blk, 0, stream>>>(
        query, key_, value, Wq, Wk, Wv, Qh, Kh, Vh, 0);
    // K2: scores + softmax(axis=j) -> f32 dist (output 2)
    scores_softmax_kernel<<<dim3(16, 128), blk, 0, stream>>>(Kh, Qh, dist);
    // K3: att = dist^T V -> bf16 att4 (row-major (j,b) x (h,d))
    att_v_kernel<<<dim3(16, 128), blk, 0, stream>>>(dist, Vh, att4);
    // K4: out = att4 @ Wo^T -> f32 d_out (output 1)
    gemm_kernel<<<dim3(8, 64, 1), blk, 0, stream>>>(
        att4, att4, att4, Wo, Wo, Wo, out, out, out, 1);
}